// Round 4
// baseline (352.948 us; speedup 1.0000x reference)
//
#include <hip/hip_runtime.h>
#include <stdint.h>

typedef unsigned short u16;
typedef short s16x8 __attribute__((ext_vector_type(8)));
typedef short s16x4 __attribute__((ext_vector_type(4)));
typedef float f32x4 __attribute__((ext_vector_type(4)));
typedef unsigned int u32x4 __attribute__((ext_vector_type(4)));

// fp32 -> bf16 bits, round-to-nearest-even (finite values)
__device__ __forceinline__ u16 f2bf(float x) {
    unsigned u = __float_as_uint(x);
    unsigned r = u + 0x7FFFu + ((u >> 16) & 1u);
    return (u16)(r >> 16);
}
__device__ __forceinline__ float bf2f(u16 h) {
    return __uint_as_float((unsigned)h << 16);
}

// async global->LDS, 16B per lane. LDS dest = wave-uniform base + lane*16.
__device__ __forceinline__ void gll16(void* lds, const void* g) {
    __builtin_amdgcn_global_load_lds(
        (const __attribute__((address_space(1))) void*)g,
        (__attribute__((address_space(3))) void*)lds,
        16, 0, 0);
}

// ---------------------------------------------------------------- weight max
// max|tanh(w)| == tanh(max|w|) (tanh monotone, odd) -> reduce raw |w| only.
__global__ __launch_bounds__(256) void reduce_maxabs(
    const float* __restrict__ a0, int n0, const float* __restrict__ a1, int n1,
    const float* __restrict__ a2, int n2, const float* __restrict__ a3, int n3,
    float* __restrict__ out) {
    int which = blockIdx.y;
    const float* w = which == 0 ? a0 : which == 1 ? a1 : which == 2 ? a2 : a3;
    int n = which == 0 ? n0 : which == 1 ? n1 : which == 2 ? n2 : n3;
    float m = 0.f;
    for (int i = blockIdx.x * 256 + threadIdx.x; i < n; i += gridDim.x * 256)
        m = fmaxf(m, fabsf(w[i]));
#pragma unroll
    for (int off = 32; off > 0; off >>= 1)
        m = fmaxf(m, __shfl_down(m, off, 64));
    __shared__ float sm[4];
    if ((threadIdx.x & 63) == 0) sm[threadIdx.x >> 6] = m;
    __syncthreads();
    if (threadIdx.x == 0) {
        m = fmaxf(fmaxf(sm[0], sm[1]), fmaxf(sm[2], sm[3]));
        atomicMax((int*)out + which, __float_as_int(m));
    }
}

// ---------------------------------------------------------------- quantize
// q = 2*round((tanh(w)/(2*tanh(max|w|))+0.5)*255)/255 - 1 -> bf16
__global__ __launch_bounds__(256) void quant_w(
    const float* __restrict__ w5, const float* __restrict__ w4,
    const float* __restrict__ w3, const float* __restrict__ w32,
    const float* __restrict__ mx,
    u16* __restrict__ q5, u16* __restrict__ q4,
    u16* __restrict__ q3, u16* __restrict__ q2) {
    int b = blockIdx.x, t = threadIdx.x;
    int which, i;
    const float* w;
    if (b < 2048)      { which = 0; w = w5;  i = b * 256 + t; }
    else if (b < 3072) { which = 1; w = w4;  i = (b - 2048) * 256 + t; }
    else if (b < 3584) { which = 2; w = w3;  i = (b - 3072) * 256 + t; }
    else               { which = 3; w = w32; i = (b - 3584) * 256 + t; }
    float inv = 0.5f / tanhf(mx[which]);
    float tt = tanhf(w[i]) * inv + 0.5f;
    float q = rintf(tt * 255.f) * (1.f / 255.f);
    u16 o = f2bf(2.f * q - 1.f);
    if (which == 0) q5[i] = o;
    else if (which == 1) q4[i] = o;
    else if (which == 2) q3[i] = o;
    else {
        // w3_2 [F=256][C=256][3][3] -> q2 [tap=kh*3+kw][F][C]
        int kw = i % 3, kh = (i / 3) % 3, c = (i / 9) & 255, f = i / 2304;
        q2[(size_t)((kh * 3 + kw) * 256 + f) * 256 + c] = o;
    }
}

// ---------------------------------------------------------------- 1x1 qconv GEMM
// A [256][K] bf16 quantized weights (k-inner). B = raw NCHW fp32 activations:
// B-tiles are staged with fused transpose+bf16-convert (coalesced dword loads
// along HW, ds_write_b64 into stride-72 padded Bs). 4 waves in 2x2 layout.
// Epilogue: +bias, optional nearest-2x upsample-add (fp32 or bf16 NHWC
// half-res), store fp32 or bf16 NHWC.
#define BSTR 72  // Bs row stride (u16): 144B, 16B-aligned fragments, pad vs 64
template<int BF, int BPX, int FJ, int FI>
__global__ __launch_bounds__(256) void gemm_qconv(
    const u16* __restrict__ A, const float* __restrict__ B,
    const float* __restrict__ bias,
    const float* __restrict__ addF, const u16* __restrict__ addB,
    float* __restrict__ outF, u16* __restrict__ outB,
    int Kfull, int Wlog, int HWlog) {
    __shared__ u16 As[BF * 64];
    __shared__ u16 Bs[BPX * BSTR];
    int t = threadIdx.x, lane = t & 63, wv = t >> 6;
    int l16 = lane & 15, quad = lane >> 4;
    int f0 = blockIdx.y * BF, p0 = blockIdx.x * BPX;
    int wf = (wv >> 1) * (BF / 2), wp = (wv & 1) * (BPX / 2);
    f32x4 acc[FJ][FI] = {};
    const u16* Ab = A + (size_t)f0 * Kfull;
    int rowA = t >> 3, c8 = t & 7;
    // B staging geometry: px tile stays inside one image (BPX <= HW)
    int n = p0 >> HWlog, hw_base = p0 & ((1 << HWlog) - 1);
    int px_off = t & (BPX - 1);            // this thread's pixel
    int cg4 = 4 * (t / BPX);               // channel-group offset (4 ch per thread-step)
    const int PG4 = 4 * (256 / BPX);       // channels covered per step
    const float* Bp = B + (((size_t)n * Kfull) << HWlog) + hw_base + px_off;
    for (int k0 = 0; k0 < Kfull; k0 += 64) {
#pragma unroll
        for (int it = 0; it < BF / 32; ++it)
            gll16(&As[(it * 256 + wv * 64) * 8], Ab + (size_t)(it * 32 + rowA) * Kfull + k0 + c8 * 8);
        // fused NCHW fp32 -> bf16 k-inner staging of B tile
#pragma unroll
        for (int s = 0; s < BPX / 16; ++s) {
            int cl = s * PG4 + cg4;        // local channel in [0,64)
            size_t cbase = (size_t)(k0 + cl) << HWlog;
            float v0 = Bp[cbase];
            float v1 = Bp[cbase + ((size_t)1 << HWlog)];
            float v2 = Bp[cbase + ((size_t)2 << HWlog)];
            float v3 = Bp[cbase + ((size_t)3 << HWlog)];
            s16x4 o;
            o.x = (short)f2bf(v0); o.y = (short)f2bf(v1);
            o.z = (short)f2bf(v2); o.w = (short)f2bf(v3);
            *(s16x4*)&Bs[px_off * BSTR + cl] = o;
        }
        __syncthreads();
#pragma unroll
        for (int kk = 0; kk < 64; kk += 32) {
            s16x8 a[FJ], b[FI];
#pragma unroll
            for (int j = 0; j < FJ; ++j)
                a[j] = *(const s16x8*)&As[(wf + 16 * j + l16) * 64 + kk + quad * 8];
#pragma unroll
            for (int i = 0; i < FI; ++i)
                b[i] = *(const s16x8*)&Bs[(wp + 16 * i + l16) * BSTR + kk + quad * 8];
#pragma unroll
            for (int j = 0; j < FJ; ++j)
#pragma unroll
                for (int i = 0; i < FI; ++i)
                    acc[j][i] = __builtin_amdgcn_mfma_f32_16x16x32_bf16(a[j], b[i], acc[j][i], 0, 0, 0);
        }
        __syncthreads();
    }
    int W = 1 << Wlog;
#pragma unroll
    for (int j = 0; j < FJ; ++j) {
        int f = f0 + wf + 16 * j + (quad << 2);
        f32x4 bz = *(const f32x4*)(bias + f);
#pragma unroll
        for (int i = 0; i < FI; ++i) {
            int px = p0 + wp + 16 * i + l16;
            f32x4 v = acc[j][i] + bz;
            if (addF || addB) {
                int nn = px >> HWlog;
                int rem = px & ((1 << HWlog) - 1);
                int h = rem >> Wlog, ww = rem & (W - 1);
                int sp = (nn << (HWlog - 2)) + ((h >> 1) << (Wlog - 1)) + (ww >> 1);
                if (addF) v += *(const f32x4*)(addF + (size_t)sp * 256 + f);
                else {
                    s16x4 av = *(const s16x4*)(addB + (size_t)sp * 256 + f);
                    v.x += bf2f((u16)av.x); v.y += bf2f((u16)av.y);
                    v.z += bf2f((u16)av.z); v.w += bf2f((u16)av.w);
                }
            }
            if (outB) {
                s16x4 o;
                o.x = (short)f2bf(v.x); o.y = (short)f2bf(v.y);
                o.z = (short)f2bf(v.z); o.w = (short)f2bf(v.w);
                *(s16x4*)(outB + (size_t)px * 256 + f) = o;
            } else {
                *(f32x4*)(outF + (size_t)px * 256 + f) = v;
            }
        }
    }
}

// ---------------------------------------------------------------- 3x3 qconv
// X [8][64][64][256] bf16 NHWC, Wq [9][256][256] bf16 tap-major, out NCHW f32.
// Round-1 proven structure: region + weight tiles both in LDS (5+4 tap split).
#define CVS 40  // padded channel stride (32 data + 8 pad) -> 80B
__global__ __launch_bounds__(256) void conv3x3_q(
    const u16* __restrict__ X, const u16* __restrict__ Wq,
    const float* __restrict__ bias, float* __restrict__ outp) {
    __shared__ u16 Rg[6 * 66 * CVS];   // halo region: rows h0-1..h0+4, w -1..64, 32 ch
    __shared__ u16 Aw[5 * 64 * CVS];   // weight tiles for up to 5 taps
    int t = threadIdx.x, lane = t & 63, wv = t >> 6;
    int l16 = lane & 15, quad = lane >> 4;
    int n = blockIdx.x >> 4, h0 = (blockIdx.x & 15) << 2;
    int f0 = blockIdx.y << 6;
    f32x4 acc[4][4] = {};
    for (int c0 = 0; c0 < 256; c0 += 32) {
#pragma unroll
        for (int it = 0; it < 7; ++it) {
            int chunk = it * 256 + t;
            if (chunk < 1584) {
                int r = chunk / 264;
                int rest = chunk - r * 264;
                int w = rest >> 2, c8 = rest & 3;
                int h = h0 - 1 + r, ww = w - 1;
                u32x4 v; v.x = 0; v.y = 0; v.z = 0; v.w = 0;
                if ((unsigned)h < 64u && (unsigned)ww < 64u)
                    v = *(const u32x4*)(X + ((((size_t)n << 12) + (h << 6) + ww) << 8) + c0 + c8 * 8);
                *(u32x4*)(Rg + (r * 66 + w) * CVS + c8 * 8) = v;
            }
        }
#pragma unroll
        for (int it = 0; it < 5; ++it) {
            int chunk = it * 256 + t;
            int tap = chunk >> 8, fr = (chunk >> 2) & 63, cc = chunk & 3;
            *(u32x4*)(Aw + (tap * 64 + fr) * CVS + cc * 8) =
                *(const u32x4*)(Wq + (((size_t)tap * 256 + f0 + fr) << 8) + c0 + cc * 8);
        }
        __syncthreads();
#pragma unroll
        for (int tp = 0; tp < 5; ++tp) {
            int dh = tp / 3, dw = tp % 3;
            s16x8 a[4], b[4];
#pragma unroll
            for (int i = 0; i < 4; ++i)
                b[i] = *(const s16x8*)(Rg + ((wv + dh) * 66 + 16 * i + l16 + dw) * CVS + quad * 8);
#pragma unroll
            for (int j = 0; j < 4; ++j)
                a[j] = *(const s16x8*)(Aw + (tp * 64 + 16 * j + l16) * CVS + quad * 8);
#pragma unroll
            for (int j = 0; j < 4; ++j)
#pragma unroll
                for (int i = 0; i < 4; ++i)
                    acc[j][i] = __builtin_amdgcn_mfma_f32_16x16x32_bf16(a[j], b[i], acc[j][i], 0, 0, 0);
        }
        __syncthreads();
#pragma unroll
        for (int it = 0; it < 4; ++it) {
            int chunk = it * 256 + t;
            int tap = 5 + (chunk >> 8), fr = (chunk >> 2) & 63, cc = chunk & 3;
            *(u32x4*)(Aw + ((tap - 5) * 64 + fr) * CVS + cc * 8) =
                *(const u32x4*)(Wq + (((size_t)tap * 256 + f0 + fr) << 8) + c0 + cc * 8);
        }
        __syncthreads();
#pragma unroll
        for (int tp = 5; tp < 9; ++tp) {
            int dh = tp / 3, dw = tp % 3;
            s16x8 a[4], b[4];
#pragma unroll
            for (int i = 0; i < 4; ++i)
                b[i] = *(const s16x8*)(Rg + ((wv + dh) * 66 + 16 * i + l16 + dw) * CVS + quad * 8);
#pragma unroll
            for (int j = 0; j < 4; ++j)
                a[j] = *(const s16x8*)(Aw + ((tp - 5) * 64 + 16 * j + l16) * CVS + quad * 8);
#pragma unroll
            for (int j = 0; j < 4; ++j)
#pragma unroll
                for (int i = 0; i < 4; ++i)
                    acc[j][i] = __builtin_amdgcn_mfma_f32_16x16x32_bf16(a[j], b[i], acc[j][i], 0, 0, 0);
        }
        __syncthreads();
    }
    int h = h0 + wv;
#pragma unroll
    for (int j = 0; j < 4; ++j) {
        int f = f0 + 16 * j + (quad << 2);
        f32x4 bz = *(const f32x4*)(bias + f);
#pragma unroll
        for (int i = 0; i < 4; ++i) {
            int w = 16 * i + l16;
#pragma unroll
            for (int r = 0; r < 4; ++r)
                outp[((size_t)(n * 256 + f + r) << 12) + (h << 6) + w] = acc[j][i][r] + bz[r];
        }
    }
}

// ---------------------------------------------------------------- launcher
extern "C" void kernel_launch(void* const* d_in, const int* in_sizes, int n_in,
                              void* d_out, int out_size, void* d_ws, size_t ws_size,
                              hipStream_t stream) {
    (void)in_sizes; (void)n_in; (void)out_size; (void)ws_size;
    const float* C3  = (const float*)d_in[0];
    const float* C4  = (const float*)d_in[1];
    const float* C5  = (const float*)d_in[2];
    const float* w5  = (const float*)d_in[3];
    const float* b5  = (const float*)d_in[4];
    const float* w4  = (const float*)d_in[5];
    const float* b4  = (const float*)d_in[6];
    const float* w3  = (const float*)d_in[7];
    const float* b3  = (const float*)d_in[8];
    const float* w32 = (const float*)d_in[9];
    const float* b32 = (const float*)d_in[10];
    float* outp = (float*)d_out;

    char* p = (char*)d_ws;
    float* mx = (float*)p;  p += 256;
    u16* q5   = (u16*)p;    p += (size_t)524288 * 2;
    u16* q4   = (u16*)p;    p += (size_t)262144 * 2;
    u16* q3   = (u16*)p;    p += (size_t)131072 * 2;
    u16* q2   = (u16*)p;    p += (size_t)589824 * 2;
    float* p5x = (float*)p; p += (size_t)2097152 * 4;   // [8,16,16,256] f32 NHWC
    u16* p4x  = (u16*)p;    p += (size_t)8388608 * 2;   // [8,32,32,256] bf16 NHWC
    u16* p3xn = (u16*)p;    p += (size_t)8388608 * 2;   // [8,64,64,256] bf16 NHWC

    hipMemsetAsync(mx, 0, 256, stream);
    reduce_maxabs<<<dim3(128, 4), 256, 0, stream>>>(w5, 524288, w4, 262144,
                                                    w3, 131072, w32, 589824, mx);
    quant_w<<<5888, 256, 0, stream>>>(w5, w4, w3, w32, mx, q5, q4, q3, q2);
    // P5 = q5 x C5 + b5            [8,16,16,256] f32, 256 blocks, no K-split
    gemm_qconv<64, 32, 2, 1><<<dim3(64, 4), 256, 0, stream>>>(
        q5, C5, b5, nullptr, nullptr, p5x, nullptr, 2048, 4, 8);
    // P4 = q4 x C4 + b4 + up2(P5)  [8,32,32,256] bf16
    gemm_qconv<64, 128, 2, 4><<<dim3(64, 4), 256, 0, stream>>>(
        q4, C4, b4, p5x, nullptr, nullptr, p4x, 1024, 5, 10);
    // P3 = q3 x C3 + b3 + up2(P4)  [8,64,64,256] bf16
    gemm_qconv<128, 128, 4, 4><<<dim3(256, 2), 256, 0, stream>>>(
        q3, C3, b3, nullptr, p4x, nullptr, p3xn, 512, 6, 12);
    // out = conv3x3(P3, q2) + b3_2 [8,256,64,64] f32 NCHW
    conv3x3_q<<<dim3(128, 4), 256, 0, stream>>>(p3xn, q2, b32, outp);
}

// Round 5
// 292.473 us; speedup vs baseline: 1.2068x; 1.2068x over previous
//
#include <hip/hip_runtime.h>
#include <stdint.h>

typedef unsigned short u16;
typedef short s16x8 __attribute__((ext_vector_type(8)));
typedef short s16x4 __attribute__((ext_vector_type(4)));
typedef float f32x4 __attribute__((ext_vector_type(4)));
typedef unsigned int u32x4 __attribute__((ext_vector_type(4)));

// fp32 -> bf16 bits, round-to-nearest-even (finite values)
__device__ __forceinline__ u16 f2bf(float x) {
    unsigned u = __float_as_uint(x);
    unsigned r = u + 0x7FFFu + ((u >> 16) & 1u);
    return (u16)(r >> 16);
}
__device__ __forceinline__ float bf2f(u16 h) {
    return __uint_as_float((unsigned)h << 16);
}

// async global->LDS, 16B per lane. LDS dest = wave-uniform base + lane*16.
__device__ __forceinline__ void gll16(void* lds, const void* g) {
    __builtin_amdgcn_global_load_lds(
        (const __attribute__((address_space(1))) void*)g,
        (__attribute__((address_space(3))) void*)lds,
        16, 0, 0);
}

// ---------------------------------------------------------------- weight max
// max|tanh(w)| == tanh(max|w|) (tanh monotone, odd) -> reduce raw |w| only.
__global__ __launch_bounds__(256) void reduce_maxabs(
    const float* __restrict__ a0, int n0, const float* __restrict__ a1, int n1,
    const float* __restrict__ a2, int n2, const float* __restrict__ a3, int n3,
    float* __restrict__ out) {
    int which = blockIdx.y;
    const float* w = which == 0 ? a0 : which == 1 ? a1 : which == 2 ? a2 : a3;
    int n = which == 0 ? n0 : which == 1 ? n1 : which == 2 ? n2 : n3;
    float m = 0.f;
    for (int i = blockIdx.x * 256 + threadIdx.x; i < n; i += gridDim.x * 256)
        m = fmaxf(m, fabsf(w[i]));
#pragma unroll
    for (int off = 32; off > 0; off >>= 1)
        m = fmaxf(m, __shfl_down(m, off, 64));
    __shared__ float sm[4];
    if ((threadIdx.x & 63) == 0) sm[threadIdx.x >> 6] = m;
    __syncthreads();
    if (threadIdx.x == 0) {
        m = fmaxf(fmaxf(sm[0], sm[1]), fmaxf(sm[2], sm[3]));
        atomicMax((int*)out + which, __float_as_int(m));
    }
}

// ---------------------------------------------------------------- quantize
// q = 2*round((tanh(w)/(2*tanh(max|w|))+0.5)*255)/255 - 1 -> bf16
__global__ __launch_bounds__(256) void quant_w(
    const float* __restrict__ w5, const float* __restrict__ w4,
    const float* __restrict__ w3, const float* __restrict__ w32,
    const float* __restrict__ mx,
    u16* __restrict__ q5, u16* __restrict__ q4,
    u16* __restrict__ q3, u16* __restrict__ q2) {
    int b = blockIdx.x, t = threadIdx.x;
    int which, i;
    const float* w;
    if (b < 2048)      { which = 0; w = w5;  i = b * 256 + t; }
    else if (b < 3072) { which = 1; w = w4;  i = (b - 2048) * 256 + t; }
    else if (b < 3584) { which = 2; w = w3;  i = (b - 3072) * 256 + t; }
    else               { which = 3; w = w32; i = (b - 3584) * 256 + t; }
    float inv = 0.5f / tanhf(mx[which]);
    float tt = tanhf(w[i]) * inv + 0.5f;
    float q = rintf(tt * 255.f) * (1.f / 255.f);
    u16 o = f2bf(2.f * q - 1.f);
    if (which == 0) q5[i] = o;
    else if (which == 1) q4[i] = o;
    else if (which == 2) q3[i] = o;
    else {
        // w3_2 [F=256][C=256][3][3] -> q2 [tap=kh*3+kw][F][C]
        int kw = i % 3, kh = (i / 3) % 3, c = (i / 9) & 255, f = i / 2304;
        q2[(size_t)((kh * 3 + kw) * 256 + f) * 256 + c] = o;
    }
}

// ---------------------------------------------------------------- NCHW f32 -> NHWC bf16
// 128c x 64hw tiles; 256B coalesced segments on BOTH load and store.
// Store-phase LDS reads use rotated row order (j'=(j+g)&7): 2-way banks (free).
__global__ __launch_bounds__(256) void transpose_nhwc(
    const float* __restrict__ C5, const float* __restrict__ C4,
    const float* __restrict__ C3,
    u16* __restrict__ c5n, u16* __restrict__ c4n, u16* __restrict__ c3n) {
    __shared__ float tile[128][65];
    int t = threadIdx.x, b = blockIdx.x;
    const float* src; u16* dst; int C, HW, cb, hwb, nn;
    if (b < 512)       { nn = b >> 6; int r = b & 63; cb = r >> 2; hwb = r & 3;
                         C = 2048; HW = 256;  src = C5; dst = c5n; }
    else if (b < 1536) { int l = b - 512;  nn = l >> 7; int r = l & 127; cb = r >> 4; hwb = r & 15;
                         C = 1024; HW = 1024; src = C4; dst = c4n; }
    else               { int l = b - 1536; nn = l >> 8; int r = l & 255; cb = r >> 6; hwb = r & 63;
                         C = 512;  HW = 4096; src = C3; dst = c3n; }
    int c0 = cb << 7, hw0 = hwb << 6;
    const float* s2 = src + (size_t)nn * C * HW;
#pragma unroll
    for (int i = 0; i < 8; ++i) {
        int c = (t >> 4) + (i << 4);
        int hw = (t & 15) << 2;
        f32x4 v = *(const f32x4*)(s2 + (size_t)(c0 + c) * HW + hw0 + hw);
        tile[c][hw] = v.x; tile[c][hw + 1] = v.y; tile[c][hw + 2] = v.z; tile[c][hw + 3] = v.w;
    }
    __syncthreads();
    u16* d2 = dst + (size_t)nn * C * HW;
    int g = t & 15;
#pragma unroll
    for (int i = 0; i < 4; ++i) {
        int hw = (t >> 4) + (i << 4);
        s16x8 o;
#pragma unroll
        for (int jj = 0; jj < 8; ++jj) {
            int j = (jj + g) & 7;   // rotate: spreads banks across lanes
            o[j] = (short)f2bf(tile[8 * g + j][hw]);
        }
        *(s16x8*)(d2 + (size_t)(hw0 + hw) * C + c0 + 8 * g) = o;
    }
}

// ---------------------------------------------------------------- 1x1 qconv GEMM
// A [256][K] bf16 weights, B [P][K] bf16 NHWC acts. Tile BF x BPX, 4 waves 2x2.
// Split-K via blockIdx.z: each z writes its own output buffer (outF + z*zstride),
// bias only at z==0. Epilogue: optional nearest-2x upsample-add of one or two
// fp32 NHWC half-res buffers (summed) or one bf16; store fp32 or bf16 NHWC.
template<int BF, int BPX, int FJ, int FI>
__global__ __launch_bounds__(256) void gemm_qconv(
    const u16* __restrict__ A, const u16* __restrict__ B,
    const float* __restrict__ bias,
    const float* __restrict__ addF, const float* __restrict__ addF2,
    const u16* __restrict__ addB,
    float* __restrict__ outF, u16* __restrict__ outB,
    int Kfull, int Kchunk, int Wlog, int HWlog, size_t zstride) {
    __shared__ u16 As[BF * 64];
    __shared__ u16 Bs[BPX * 64];
    int t = threadIdx.x, lane = t & 63, wv = t >> 6;
    int l16 = lane & 15, quad = lane >> 4;
    int f0 = blockIdx.y * BF, p0 = blockIdx.x * BPX;
    int wf = (wv >> 1) * (BF / 2), wp = (wv & 1) * (BPX / 2);
    f32x4 acc[FJ][FI] = {};
    const u16* Ab = A + (size_t)f0 * Kfull;
    const u16* Bb = B + (size_t)p0 * Kfull;
    int row = t >> 3, c8 = t & 7;
    int k_begin = blockIdx.z * Kchunk, k_end = k_begin + Kchunk;
    for (int k0 = k_begin; k0 < k_end; k0 += 64) {
#pragma unroll
        for (int it = 0; it < BF / 32; ++it)
            gll16(&As[(it * 256 + wv * 64) * 8], Ab + (size_t)(it * 32 + row) * Kfull + k0 + c8 * 8);
#pragma unroll
        for (int it = 0; it < BPX / 32; ++it)
            gll16(&Bs[(it * 256 + wv * 64) * 8], Bb + (size_t)(it * 32 + row) * Kfull + k0 + c8 * 8);
        __syncthreads();
#pragma unroll
        for (int kk = 0; kk < 64; kk += 32) {
            s16x8 a[FJ], b[FI];
#pragma unroll
            for (int j = 0; j < FJ; ++j)
                a[j] = *(const s16x8*)&As[(wf + 16 * j + l16) * 64 + kk + quad * 8];
#pragma unroll
            for (int i = 0; i < FI; ++i)
                b[i] = *(const s16x8*)&Bs[(wp + 16 * i + l16) * 64 + kk + quad * 8];
#pragma unroll
            for (int j = 0; j < FJ; ++j)
#pragma unroll
                for (int i = 0; i < FI; ++i)
                    acc[j][i] = __builtin_amdgcn_mfma_f32_16x16x32_bf16(a[j], b[i], acc[j][i], 0, 0, 0);
        }
        __syncthreads();
    }
    int W = 1 << Wlog;
    bool bias_on = (blockIdx.z == 0);
    float* outFz = outF ? outF + blockIdx.z * zstride : outF;
#pragma unroll
    for (int j = 0; j < FJ; ++j) {
        int f = f0 + wf + 16 * j + (quad << 2);
        f32x4 bz = {0.f, 0.f, 0.f, 0.f};
        if (bias_on && bias) bz = *(const f32x4*)(bias + f);
#pragma unroll
        for (int i = 0; i < FI; ++i) {
            int px = p0 + wp + 16 * i + l16;
            f32x4 v = acc[j][i] + bz;
            if (addF || addB) {
                int nn = px >> HWlog;
                int rem = px & ((1 << HWlog) - 1);
                int h = rem >> Wlog, ww = rem & (W - 1);
                int sp = (nn << (HWlog - 2)) + ((h >> 1) << (Wlog - 1)) + (ww >> 1);
                if (addF) {
                    f32x4 s = *(const f32x4*)(addF + (size_t)sp * 256 + f);
                    if (addF2) s += *(const f32x4*)(addF2 + (size_t)sp * 256 + f);
                    v += s;
                } else {
                    s16x4 av = *(const s16x4*)(addB + (size_t)sp * 256 + f);
                    v.x += bf2f((u16)av.x); v.y += bf2f((u16)av.y);
                    v.z += bf2f((u16)av.z); v.w += bf2f((u16)av.w);
                }
            }
            if (outB) {
                s16x4 o;
                o.x = (short)f2bf(v.x); o.y = (short)f2bf(v.y);
                o.z = (short)f2bf(v.z); o.w = (short)f2bf(v.w);
                *(s16x4*)(outB + (size_t)px * 256 + f) = o;
            } else {
                *(f32x4*)(outFz + (size_t)px * 256 + f) = v;
            }
        }
    }
}

// ---------------------------------------------------------------- 3x3 qconv
// X [8][64][64][256] bf16 NHWC, Wq [9][256][256] bf16 tap-major, out NCHW f32.
// Proven round-1 structure: region + weight tiles both in LDS (5+4 tap split).
#define CVS 40  // padded channel stride (32 data + 8 pad) -> 80B
__global__ __launch_bounds__(256) void conv3x3_q(
    const u16* __restrict__ X, const u16* __restrict__ Wq,
    const float* __restrict__ bias, float* __restrict__ outp) {
    __shared__ u16 Rg[6 * 66 * CVS];   // halo region: rows h0-1..h0+4, w -1..64, 32 ch
    __shared__ u16 Aw[5 * 64 * CVS];   // weight tiles for up to 5 taps
    int t = threadIdx.x, lane = t & 63, wv = t >> 6;
    int l16 = lane & 15, quad = lane >> 4;
    int n = blockIdx.x >> 4, h0 = (blockIdx.x & 15) << 2;
    int f0 = blockIdx.y << 6;
    f32x4 acc[4][4] = {};
    for (int c0 = 0; c0 < 256; c0 += 32) {
#pragma unroll
        for (int it = 0; it < 7; ++it) {
            int chunk = it * 256 + t;
            if (chunk < 1584) {
                int r = chunk / 264;
                int rest = chunk - r * 264;
                int w = rest >> 2, c8 = rest & 3;
                int h = h0 - 1 + r, ww = w - 1;
                u32x4 v; v.x = 0; v.y = 0; v.z = 0; v.w = 0;
                if ((unsigned)h < 64u && (unsigned)ww < 64u)
                    v = *(const u32x4*)(X + ((((size_t)n << 12) + (h << 6) + ww) << 8) + c0 + c8 * 8);
                *(u32x4*)(Rg + (r * 66 + w) * CVS + c8 * 8) = v;
            }
        }
#pragma unroll
        for (int it = 0; it < 5; ++it) {
            int chunk = it * 256 + t;
            int tap = chunk >> 8, fr = (chunk >> 2) & 63, cc = chunk & 3;
            *(u32x4*)(Aw + (tap * 64 + fr) * CVS + cc * 8) =
                *(const u32x4*)(Wq + (((size_t)tap * 256 + f0 + fr) << 8) + c0 + cc * 8);
        }
        __syncthreads();
#pragma unroll
        for (int tp = 0; tp < 5; ++tp) {
            int dh = tp / 3, dw = tp % 3;
            s16x8 a[4], b[4];
#pragma unroll
            for (int i = 0; i < 4; ++i)
                b[i] = *(const s16x8*)(Rg + ((wv + dh) * 66 + 16 * i + l16 + dw) * CVS + quad * 8);
#pragma unroll
            for (int j = 0; j < 4; ++j)
                a[j] = *(const s16x8*)(Aw + (tp * 64 + 16 * j + l16) * CVS + quad * 8);
#pragma unroll
            for (int j = 0; j < 4; ++j)
#pragma unroll
                for (int i = 0; i < 4; ++i)
                    acc[j][i] = __builtin_amdgcn_mfma_f32_16x16x32_bf16(a[j], b[i], acc[j][i], 0, 0, 0);
        }
        __syncthreads();
#pragma unroll
        for (int it = 0; it < 4; ++it) {
            int chunk = it * 256 + t;
            int tap = 5 + (chunk >> 8), fr = (chunk >> 2) & 63, cc = chunk & 3;
            *(u32x4*)(Aw + ((tap - 5) * 64 + fr) * CVS + cc * 8) =
                *(const u32x4*)(Wq + (((size_t)tap * 256 + f0 + fr) << 8) + c0 + cc * 8);
        }
        __syncthreads();
#pragma unroll
        for (int tp = 5; tp < 9; ++tp) {
            int dh = tp / 3, dw = tp % 3;
            s16x8 a[4], b[4];
#pragma unroll
            for (int i = 0; i < 4; ++i)
                b[i] = *(const s16x8*)(Rg + ((wv + dh) * 66 + 16 * i + l16 + dw) * CVS + quad * 8);
#pragma unroll
            for (int j = 0; j < 4; ++j)
                a[j] = *(const s16x8*)(Aw + ((tp - 5) * 64 + 16 * j + l16) * CVS + quad * 8);
#pragma unroll
            for (int j = 0; j < 4; ++j)
#pragma unroll
                for (int i = 0; i < 4; ++i)
                    acc[j][i] = __builtin_amdgcn_mfma_f32_16x16x32_bf16(a[j], b[i], acc[j][i], 0, 0, 0);
        }
        __syncthreads();
    }
    int h = h0 + wv;
#pragma unroll
    for (int j = 0; j < 4; ++j) {
        int f = f0 + 16 * j + (quad << 2);
        f32x4 bz = *(const f32x4*)(bias + f);
#pragma unroll
        for (int i = 0; i < 4; ++i) {
            int w = 16 * i + l16;
#pragma unroll
            for (int r = 0; r < 4; ++r)
                outp[((size_t)(n * 256 + f + r) << 12) + (h << 6) + w] = acc[j][i][r] + bz[r];
        }
    }
}

// ---------------------------------------------------------------- launcher
extern "C" void kernel_launch(void* const* d_in, const int* in_sizes, int n_in,
                              void* d_out, int out_size, void* d_ws, size_t ws_size,
                              hipStream_t stream) {
    (void)in_sizes; (void)n_in; (void)out_size; (void)ws_size;
    const float* C3  = (const float*)d_in[0];
    const float* C4  = (const float*)d_in[1];
    const float* C5  = (const float*)d_in[2];
    const float* w5  = (const float*)d_in[3];
    const float* b5  = (const float*)d_in[4];
    const float* w4  = (const float*)d_in[5];
    const float* b4  = (const float*)d_in[6];
    const float* w3  = (const float*)d_in[7];
    const float* b3  = (const float*)d_in[8];
    const float* w32 = (const float*)d_in[9];
    const float* b32 = (const float*)d_in[10];
    float* outp = (float*)d_out;

    char* p = (char*)d_ws;
    float* mx = (float*)p;  p += 256;
    u16* q5   = (u16*)p;    p += (size_t)524288 * 2;
    u16* q4   = (u16*)p;    p += (size_t)262144 * 2;
    u16* q3   = (u16*)p;    p += (size_t)131072 * 2;
    u16* q2   = (u16*)p;    p += (size_t)589824 * 2;
    u16* c5n  = (u16*)p;    p += (size_t)4194304 * 2;
    u16* c4n  = (u16*)p;    p += (size_t)8388608 * 2;
    u16* c3n  = (u16*)p;    p += (size_t)16777216 * 2;
    float* p5xa = (float*)p; p += (size_t)2097152 * 4;  // [8,16,16,256] f32, z=0 half
    float* p5xb = (float*)p; p += (size_t)2097152 * 4;  // z=1 half
    u16* p4x  = (u16*)p;    p += (size_t)8388608 * 2;   // [8,32,32,256] bf16
    u16* p3xn = (u16*)p;    p += (size_t)8388608 * 2;   // [8,64,64,256] bf16

    hipMemsetAsync(mx, 0, 256, stream);
    reduce_maxabs<<<dim3(128, 4), 256, 0, stream>>>(w5, 524288, w4, 262144,
                                                    w3, 131072, w32, 589824, mx);
    quant_w<<<5888, 256, 0, stream>>>(w5, w4, w3, w32, mx, q5, q4, q3, q2);
    transpose_nhwc<<<3584, 256, 0, stream>>>(C5, C4, C3, c5n, c4n, c3n);
    // P5 = q5 x C5 + b5            split-K=2 into p5xa/p5xb (no atomics)
    gemm_qconv<64, 64, 2, 2><<<dim3(32, 4, 2), 256, 0, stream>>>(
        q5, c5n, b5, nullptr, nullptr, nullptr, p5xa, nullptr,
        2048, 1024, 4, 8, (size_t)2097152);
    // P4 = q4 x C4 + b4 + up2(p5xa + p5xb)   [8,32,32,256] bf16
    gemm_qconv<64, 128, 2, 4><<<dim3(64, 4, 1), 256, 0, stream>>>(
        q4, c4n, b4, p5xa, p5xb, nullptr, nullptr, p4x,
        1024, 1024, 5, 10, 0);
    // P3 = q3 x C3 + b3 + up2(P4)            [8,64,64,256] bf16
    gemm_qconv<128, 128, 4, 4><<<dim3(256, 2, 1), 256, 0, stream>>>(
        q3, c3n, b3, nullptr, nullptr, p4x, nullptr, p3xn,
        512, 512, 6, 12, 0);
    // out = conv3x3(P3, q2) + b3_2           [8,256,64,64] f32 NCHW
    conv3x3_q<<<dim3(128, 4), 256, 0, stream>>>(p3xn, q2, b32, outp);
}